// Round 8
// baseline (242.163 us; speedup 1.0000x reference)
//
#include <hip/hip_runtime.h>
#include <stdint.h>

#define B_SZ   2048
#define IN_SZ  1024
#define OUT_SZ 1024
#define Q_SZ   16

typedef __attribute__((ext_vector_type(8))) short short8;   // 8 bf16 (4 VGPRs)
typedef __attribute__((ext_vector_type(4))) float floatx4;  // MFMA accumulator
typedef __attribute__((ext_vector_type(2))) unsigned short u16x2;

__device__ __forceinline__ unsigned short f32_to_bf16_rne(float f) {
    union { float f; uint32_t u; } v; v.f = f;
    uint32_t u = v.u;
    return (unsigned short)((u + 0x7FFFu + ((u >> 16) & 1u)) >> 16);
}

// packed 2x16-bit: out = (iv16==q16) ? xv16 : 0.  t=iv^qq; m=min(t,1)-1
// (0xFFFF iff t==0 since idx,q<16); return x & m.  Exact.
__device__ __forceinline__ uint32_t mask2(uint32_t xv, uint32_t iv, uint32_t qq) {
    union { uint32_t u; u16x2 v; } t, m;
    t.u = iv ^ qq;
    u16x2 one; one.x = 1; one.y = 1;
    m.v = __builtin_elementwise_min(t.v, one) - one;
    return xv & m.u;
}

// ---------------- prep: fragment-linear Wf ----------------
// Slab S = (zb*8+xb)*32 + ih*16 + q   (16 KB each; 2048 slabs = 32 MB)
// chunk c = (h*8+nt)*64 + lane, 16B:  element j of lane's B-frag =
//   bf16( W[(q*1024 + i)*1024 + o] ),  o = xb*128+nt*16+(lane&15),
//   i = zb*128 + ih*64 + h*32 + (lane>>4)*8 + j
__global__ void k_build_wf(const float* __restrict__ W, unsigned short* __restrict__ Wf) {
    const int S = blockIdx.x;
    const int q  = S & 15, ih = (S >> 4) & 1, xb = (S >> 5) & 7, zb = S >> 8;
    const int t = threadIdx.x;
    unsigned short* dst = Wf + (size_t)S * 8192;
#pragma unroll
    for (int it = 0; it < 4; ++it) {
        int c = it * 256 + t;
        int L = c & 63;
        int hnt = c >> 6;                      // h*8+nt
        int h = hnt >> 3, nt = hnt & 7;
        int o  = xb * 128 + nt * 16 + (L & 15);
        int i0 = zb * 128 + ih * 64 + h * 32 + (L >> 4) * 8;
        const float* src = W + ((size_t)(q * 1024 + i0)) * 1024 + o;
        unsigned short v[8];
#pragma unroll
        for (int j = 0; j < 8; ++j) v[j] = f32_to_bf16_rne(src[(size_t)j * 1024]);
        *(uint4*)(dst + (size_t)c * 8) = *(uint4*)v;
    }
}

// ---------------- fused GEMM, LDS-free, register-pipelined, NO barriers --------
// Block: 128b x 128o x (i-window 128, all 16 q). Wave: 32b x 128o.
// B-frags double-buffered in registers at half-step granularity: each 8-load
// group is issued >=1 full MFMA block (~310 cyc) before its first use, so the
// compiler's vmcnt waits are already satisfied. No barriers -> waves self-
// schedule; per-(xb,zb) Wf window is 512 KB, 8 windows/XCD = 4 MB = L2.
__global__ __launch_bounds__(256, 2) void k_gemm(const unsigned short* __restrict__ Wf,
                                                 const float* __restrict__ x,
                                                 const int* __restrict__ idx,
                                                 const float* __restrict__ bias,
                                                 float* __restrict__ out) {
    const int tid  = threadIdx.x;
    const int wave = tid >> 6, lane = tid & 63;

    // id = zb + 8*xb + 64*yb -> XCD (id%8) = zb
    const int id = blockIdx.x;
    const int zb = id & 7;
    const int xb = (id >> 3) & 7;
    const int yb = id >> 6;
    const int o0 = xb * 128, b0 = yb * 128, ibase = zb * 128;

    // uniform slab base + constant per-lane offset (SGPR-friendly addressing)
    const char* wbase = (const char*)Wf + ((size_t)(zb * 8 + xb) * 32) * 16384;
    const int   lofs  = lane * 16;

    const int arow = b0 + wave * 32 + (lane & 15);
    const float* xg = x + (size_t)arow * IN_SZ + ibase + (lane >> 4) * 8;
    const int*   ig = idx + (size_t)arow * IN_SZ + ibase + (lane >> 4) * 8;

    floatx4 acc[16];
#pragma unroll
    for (int i = 0; i < 16; ++i) acc[i] = (floatx4){0.f, 0.f, 0.f, 0.f};

    uint4 xr[2][2], ir[2][2];
    short8 bA[8], bB[8];

    // load the 8 B-frags of (s, h) into d[]
#define LOADB(d, s, h)                                                        \
    {   const char* p_ = wbase + (size_t)(s) * 16384 + (h) * 8192 + lofs;     \
        _Pragma("unroll")                                                     \
        for (int nt_ = 0; nt_ < 8; ++nt_)                                     \
            (d)[nt_] = *(const short8*)(p_ + nt_ * 1024);                     \
    }

    // load + convert A regs for i-half ih (i in [ih*64, ih*64+64) of window)
#define RELOADA(ih)                                                           \
    {   int io_ = (ih) * 64;                                                  \
        _Pragma("unroll")                                                     \
        for (int mt_ = 0; mt_ < 2; ++mt_)                                     \
            _Pragma("unroll")                                                 \
            for (int hh_ = 0; hh_ < 2; ++hh_) {                               \
                const float* xp_ = xg + mt_ * 16 * IN_SZ + io_ + hh_ * 32;    \
                const int*   ip_ = ig + mt_ * 16 * IN_SZ + io_ + hh_ * 32;    \
                float a_[8]; int b_[8];                                       \
                *(float4*)(a_)     = *(const float4*)xp_;                     \
                *(float4*)(a_ + 4) = *((const float4*)xp_ + 1);               \
                *(int4*)(b_)       = *(const int4*)ip_;                       \
                *(int4*)(b_ + 4)   = *((const int4*)ip_ + 1);                 \
                unsigned short xv_[8];                                        \
                _Pragma("unroll")                                             \
                for (int j_ = 0; j_ < 8; ++j_) xv_[j_] = f32_to_bf16_rne(a_[j_]); \
                xr[mt_][hh_] = *(uint4*)xv_;                                  \
                uint32_t iw_[4];                                              \
                _Pragma("unroll")                                             \
                for (int w_ = 0; w_ < 4; ++w_)                                \
                    iw_[w_] = ((uint32_t)b_[2 * w_] & 0xFFFFu) |              \
                              ((uint32_t)b_[2 * w_ + 1] << 16);               \
                ir[mt_][hh_] = *(uint4*)iw_;                                  \
            }                                                                 \
    }

    RELOADA(0);
    LOADB(bA, 0, 0);

    for (int s = 0; s < 32; ++s) {
        if (s == 16) RELOADA(1);
        LOADB(bB, s, 1);                       // covered by h=0 MFMA block
        const uint32_t qq = (uint32_t)(s & 15) * 0x00010001u;

        union { uint4 u; short8 s8; } aF[2];
#pragma unroll
        for (int mt = 0; mt < 2; ++mt) {       // masks for h=0
            aF[mt].u.x = mask2(xr[mt][0].x, ir[mt][0].x, qq);
            aF[mt].u.y = mask2(xr[mt][0].y, ir[mt][0].y, qq);
            aF[mt].u.z = mask2(xr[mt][0].z, ir[mt][0].z, qq);
            aF[mt].u.w = mask2(xr[mt][0].w, ir[mt][0].w, qq);
        }
#pragma unroll
        for (int mt = 0; mt < 2; ++mt)         // MFMA h=0 (consumes bA)
#pragma unroll
            for (int nt = 0; nt < 8; ++nt)
                acc[mt * 8 + nt] = __builtin_amdgcn_mfma_f32_16x16x32_bf16(
                    aF[mt].s8, bA[nt], acc[mt * 8 + nt], 0, 0, 0);

        if (s < 31) LOADB(bA, s + 1, 0);       // covered by h=1 MFMA block

#pragma unroll
        for (int mt = 0; mt < 2; ++mt) {       // masks for h=1
            aF[mt].u.x = mask2(xr[mt][1].x, ir[mt][1].x, qq);
            aF[mt].u.y = mask2(xr[mt][1].y, ir[mt][1].y, qq);
            aF[mt].u.z = mask2(xr[mt][1].z, ir[mt][1].z, qq);
            aF[mt].u.w = mask2(xr[mt][1].w, ir[mt][1].w, qq);
        }
#pragma unroll
        for (int mt = 0; mt < 2; ++mt)         // MFMA h=1 (consumes bB)
#pragma unroll
            for (int nt = 0; nt < 8; ++nt)
                acc[mt * 8 + nt] = __builtin_amdgcn_mfma_f32_16x16x32_bf16(
                    aF[mt].s8, bB[nt], acc[mt * 8 + nt], 0, 0, 0);
    }

    // epilogue: C/D col=lane&15 (o), row=(lane>>4)*4+reg (b); zb==0 adds bias
    int cn = lane & 15, rq = lane >> 4;
    float bv[8];
#pragma unroll
    for (int nt = 0; nt < 8; ++nt)
        bv[nt] = (zb == 0) ? bias[o0 + nt * 16 + cn] : 0.0f;
#pragma unroll
    for (int mt = 0; mt < 2; ++mt)
#pragma unroll
        for (int nt = 0; nt < 8; ++nt) {
            int bb = b0 + wave * 32 + mt * 16 + rq * 4;
            int oo = o0 + nt * 16 + cn;
#pragma unroll
            for (int e = 0; e < 4; ++e)
                atomicAdd(out + (size_t)(bb + e) * OUT_SZ + oo, acc[mt * 8 + nt][e] + bv[nt]);
        }
#undef LOADB
#undef RELOADA
}

// ---------------- fallback (ws too small): exact fp32 gather ----------------
__global__ void k_naive(const float* __restrict__ x, const int* __restrict__ idx,
                        const float* __restrict__ W, const float* __restrict__ bias,
                        float* __restrict__ out) {
    int b = blockIdx.x;
    int o = threadIdx.x * 4;
    float4 acc = *(const float4*)(bias + o);
    const float* xr = x + (size_t)b * IN_SZ;
    const int*   ir = idx + (size_t)b * IN_SZ;
    for (int i = 0; i < IN_SZ; ++i) {
        float xv = xr[i];
        int q = ir[i];
        float4 w4 = *(const float4*)(W + ((size_t)q * IN_SZ + i) * OUT_SZ + o);
        acc.x += xv * w4.x; acc.y += xv * w4.y;
        acc.z += xv * w4.z; acc.w += xv * w4.w;
    }
    *(float4*)(out + (size_t)b * OUT_SZ + o) = acc;
}

extern "C" void kernel_launch(void* const* d_in, const int* in_sizes, int n_in,
                              void* d_out, int out_size, void* d_ws, size_t ws_size,
                              hipStream_t stream) {
    const float* x    = (const float*)d_in[0];
    const int*   idx  = (const int*)d_in[1];
    const float* W    = (const float*)d_in[2];
    const float* bias = (const float*)d_in[3];
    float* out = (float*)d_out;

    const size_t wf_bytes = (size_t)2048 * 16384;            // 32 MB frag-linear Wt
    if (ws_size < wf_bytes) {
        k_naive<<<dim3(B_SZ), dim3(256), 0, stream>>>(x, idx, W, bias, out);
        return;
    }
    unsigned short* Wf = (unsigned short*)d_ws;

    hipMemsetAsync(d_out, 0, (size_t)out_size * sizeof(float), stream);
    k_build_wf<<<dim3(2048), dim3(256), 0, stream>>>(W, Wf);
    k_gemm<<<dim3(8 * 8 * (B_SZ / 128)), dim3(256), 0, stream>>>(Wf, x, idx, bias, out);
}

// Round 9
// 209.906 us; speedup vs baseline: 1.1537x; 1.1537x over previous
//
#include <hip/hip_runtime.h>
#include <stdint.h>

#define B_SZ   2048
#define IN_SZ  1024
#define OUT_SZ 1024
#define Q_SZ   16
#define NZB    4                              // i-windows of 256

typedef __attribute__((ext_vector_type(8))) short short8;   // 8 bf16 (4 VGPRs)
typedef __attribute__((ext_vector_type(4))) float floatx4;  // MFMA accumulator
typedef __attribute__((ext_vector_type(2))) unsigned short u16x2;

__device__ __forceinline__ unsigned short f32_to_bf16_rne(float f) {
    union { float f; uint32_t u; } v; v.f = f;
    uint32_t u = v.u;
    return (unsigned short)((u + 0x7FFFu + ((u >> 16) & 1u)) >> 16);
}

// packed 2x16-bit: out = (iv16==q16) ? xv16 : 0.  t=iv^qq; m=min(t,1)-1
// (0xFFFF iff t==0 since idx,q<16); return x & m.  Exact.
__device__ __forceinline__ uint32_t mask2(uint32_t xv, uint32_t iv, uint32_t qq) {
    union { uint32_t u; u16x2 v; } t, m;
    t.u = iv ^ qq;
    u16x2 one; one.x = 1; one.y = 1;
    m.v = __builtin_elementwise_min(t.v, one) - one;
    return xv & m.u;
}

// ---------------- prep: fragment-linear Wf ----------------
// Window (zb in 0..3, xb in 0..7): o in [xb*128,+128), i in [zb*256,+256).
// Slab S = (zb*8+xb)*64 + ih*16 + q  (16 KB each; 2048 slabs = 32 MB)
// chunk c = (h*8+nt)*64 + lane:  element j of lane's B-frag =
//   bf16( W[(q*1024 + i)*1024 + o] ),  o = xb*128+nt*16+(lane&15),
//   i = zb*256 + ih*64 + h*32 + (lane>>4)*8 + j
__global__ void k_build_wf(const float* __restrict__ W, unsigned short* __restrict__ Wf) {
    const int S = blockIdx.x;
    const int q  = S & 15, ih = (S >> 4) & 3, xb = (S >> 6) & 7, zb = S >> 9;
    const int t = threadIdx.x;
    unsigned short* dst = Wf + (size_t)S * 8192;
#pragma unroll
    for (int it = 0; it < 4; ++it) {
        int c = it * 256 + t;
        int L = c & 63;
        int hnt = c >> 6;                      // h*8+nt
        int h = hnt >> 3, nt = hnt & 7;
        int o  = xb * 128 + nt * 16 + (L & 15);
        int i0 = zb * 256 + ih * 64 + h * 32 + (L >> 4) * 8;
        const float* src = W + ((size_t)(q * 1024 + i0)) * 1024 + o;
        unsigned short v[8];
#pragma unroll
        for (int j = 0; j < 8; ++j) v[j] = f32_to_bf16_rne(src[(size_t)j * 1024]);
        *(uint4*)(dst + (size_t)c * 8) = *(uint4*)v;
    }
}

// ---------------- fused GEMM, LDS-free, register-pipelined, NO atomics --------
// Block: 128b x 128o x (i-window 256, all 16 q) -> 64 steps. Wave: 32b x 128o.
// Epilogue writes plain stores to the block's PRIVATE partial buffer P[zb]
// (no cross-XCD atomic RMW -- the suspected serializer of R1..R8).
__global__ __launch_bounds__(256, 2) void k_gemm(const unsigned short* __restrict__ Wf,
                                                 const float* __restrict__ x,
                                                 const int* __restrict__ idx,
                                                 float* __restrict__ P) {
    const int tid  = threadIdx.x;
    const int wave = tid >> 6, lane = tid & 63;

    // id = zb + 4*xb + 32*yb -> XCD (id%8) = zb+4*(xb&1), constant per window;
    // the 16 yb-blocks sharing a 1 MB window land on one XCD (4 windows = 4 MB L2).
    const int id = blockIdx.x;
    const int zb = id & 3;
    const int xb = (id >> 2) & 7;
    const int yb = id >> 5;
    const int o0 = xb * 128, b0 = yb * 128, ibase = zb * 256;

    const char* wbase = (const char*)Wf + (size_t)(zb * 8 + xb) * 64 * 16384;
    const int   lofs  = lane * 16;

    const int arow = b0 + wave * 32 + (lane & 15);
    const float* xg = x + (size_t)arow * IN_SZ + ibase + (lane >> 4) * 8;
    const int*   ig = idx + (size_t)arow * IN_SZ + ibase + (lane >> 4) * 8;

    floatx4 acc[16];
#pragma unroll
    for (int i = 0; i < 16; ++i) acc[i] = (floatx4){0.f, 0.f, 0.f, 0.f};

    uint4 xr[2][2], ir[2][2];
    short8 bA[8], bB[8];

#define LOADB(d, s, h)                                                        \
    {   const char* p_ = wbase + (size_t)(s) * 16384 + (h) * 8192 + lofs;     \
        _Pragma("unroll")                                                     \
        for (int nt_ = 0; nt_ < 8; ++nt_)                                     \
            (d)[nt_] = *(const short8*)(p_ + nt_ * 1024);                     \
    }

#define RELOADA(ih)                                                           \
    {   int io_ = (ih) * 64;                                                  \
        _Pragma("unroll")                                                     \
        for (int mt_ = 0; mt_ < 2; ++mt_)                                     \
            _Pragma("unroll")                                                 \
            for (int hh_ = 0; hh_ < 2; ++hh_) {                               \
                const float* xp_ = xg + mt_ * 16 * IN_SZ + io_ + hh_ * 32;    \
                const int*   ip_ = ig + mt_ * 16 * IN_SZ + io_ + hh_ * 32;    \
                float a_[8]; int b_[8];                                       \
                *(float4*)(a_)     = *(const float4*)xp_;                     \
                *(float4*)(a_ + 4) = *((const float4*)xp_ + 1);               \
                *(int4*)(b_)       = *(const int4*)ip_;                       \
                *(int4*)(b_ + 4)   = *((const int4*)ip_ + 1);                 \
                unsigned short xv_[8];                                        \
                _Pragma("unroll")                                             \
                for (int j_ = 0; j_ < 8; ++j_) xv_[j_] = f32_to_bf16_rne(a_[j_]); \
                xr[mt_][hh_] = *(uint4*)xv_;                                  \
                uint32_t iw_[4];                                              \
                _Pragma("unroll")                                             \
                for (int w_ = 0; w_ < 4; ++w_)                                \
                    iw_[w_] = ((uint32_t)b_[2 * w_] & 0xFFFFu) |              \
                              ((uint32_t)b_[2 * w_ + 1] << 16);               \
                ir[mt_][hh_] = *(uint4*)iw_;                                  \
            }                                                                 \
    }

    RELOADA(0);
    LOADB(bA, 0, 0);

    for (int s = 0; s < 64; ++s) {
        if (s && (s & 15) == 0) RELOADA(s >> 4);
        LOADB(bB, s, 1);                       // covered by h=0 MFMA block
        const uint32_t qq = (uint32_t)(s & 15) * 0x00010001u;

        union { uint4 u; short8 s8; } aF[2];
#pragma unroll
        for (int mt = 0; mt < 2; ++mt) {       // masks for h=0
            aF[mt].u.x = mask2(xr[mt][0].x, ir[mt][0].x, qq);
            aF[mt].u.y = mask2(xr[mt][0].y, ir[mt][0].y, qq);
            aF[mt].u.z = mask2(xr[mt][0].z, ir[mt][0].z, qq);
            aF[mt].u.w = mask2(xr[mt][0].w, ir[mt][0].w, qq);
        }
#pragma unroll
        for (int mt = 0; mt < 2; ++mt)         // MFMA h=0 (consumes bA)
#pragma unroll
            for (int nt = 0; nt < 8; ++nt)
                acc[mt * 8 + nt] = __builtin_amdgcn_mfma_f32_16x16x32_bf16(
                    aF[mt].s8, bA[nt], acc[mt * 8 + nt], 0, 0, 0);

        if (s < 63) LOADB(bA, s + 1, 0);       // covered by h=1 MFMA block

#pragma unroll
        for (int mt = 0; mt < 2; ++mt) {       // masks for h=1
            aF[mt].u.x = mask2(xr[mt][1].x, ir[mt][1].x, qq);
            aF[mt].u.y = mask2(xr[mt][1].y, ir[mt][1].y, qq);
            aF[mt].u.z = mask2(xr[mt][1].z, ir[mt][1].z, qq);
            aF[mt].u.w = mask2(xr[mt][1].w, ir[mt][1].w, qq);
        }
#pragma unroll
        for (int mt = 0; mt < 2; ++mt)         // MFMA h=1 (consumes bB)
#pragma unroll
            for (int nt = 0; nt < 8; ++nt)
                acc[mt * 8 + nt] = __builtin_amdgcn_mfma_f32_16x16x32_bf16(
                    aF[mt].s8, bB[nt], acc[mt * 8 + nt], 0, 0, 0);
    }

    // epilogue: plain stores to private partial buffer (C/D: col=lane&15 -> o,
    // row=(lane>>4)*4+e -> b). No atomics anywhere.
    float* Pz = P + (size_t)zb * (B_SZ * OUT_SZ);
    int cn = lane & 15, rq = lane >> 4;
#pragma unroll
    for (int mt = 0; mt < 2; ++mt)
#pragma unroll
        for (int nt = 0; nt < 8; ++nt) {
            int bb = b0 + wave * 32 + mt * 16 + rq * 4;
            int oo = o0 + nt * 16 + cn;
#pragma unroll
            for (int e = 0; e < 4; ++e)
                Pz[(size_t)(bb + e) * OUT_SZ + oo] = acc[mt * 8 + nt][e];
        }
#undef LOADB
#undef RELOADA
}

// ---------------- reduce: out = bias + sum_z P[z] ----------------
__global__ void k_reduce(const float* __restrict__ P, const float* __restrict__ bias,
                         float* __restrict__ out) {
    int t = blockIdx.x * 256 + threadIdx.x;    // float4 index, 524288 total
    const float4* b4 = (const float4*)bias;
    float4 a = b4[t & 255];
#pragma unroll
    for (int z = 0; z < NZB; ++z) {
        float4 v = ((const float4*)P)[(size_t)z * (B_SZ * OUT_SZ / 4) + t];
        a.x += v.x; a.y += v.y; a.z += v.z; a.w += v.w;
    }
    ((float4*)out)[t] = a;
}

// ---------------- fallback (ws too small): exact fp32 gather ----------------
__global__ void k_naive(const float* __restrict__ x, const int* __restrict__ idx,
                        const float* __restrict__ W, const float* __restrict__ bias,
                        float* __restrict__ out) {
    int b = blockIdx.x;
    int o = threadIdx.x * 4;
    float4 acc = *(const float4*)(bias + o);
    const float* xr = x + (size_t)b * IN_SZ;
    const int*   ir = idx + (size_t)b * IN_SZ;
    for (int i = 0; i < IN_SZ; ++i) {
        float xv = xr[i];
        int q = ir[i];
        float4 w4 = *(const float4*)(W + ((size_t)q * IN_SZ + i) * OUT_SZ + o);
        acc.x += xv * w4.x; acc.y += xv * w4.y;
        acc.z += xv * w4.z; acc.w += xv * w4.w;
    }
    *(float4*)(out + (size_t)b * OUT_SZ + o) = acc;
}

extern "C" void kernel_launch(void* const* d_in, const int* in_sizes, int n_in,
                              void* d_out, int out_size, void* d_ws, size_t ws_size,
                              hipStream_t stream) {
    const float* x    = (const float*)d_in[0];
    const int*   idx  = (const int*)d_in[1];
    const float* W    = (const float*)d_in[2];
    const float* bias = (const float*)d_in[3];
    float* out = (float*)d_out;

    const size_t wf_bytes = (size_t)2048 * 16384;                 // 32 MB frag-linear W
    const size_t p_bytes  = (size_t)NZB * B_SZ * OUT_SZ * 4;      // 32 MB partials
    if (ws_size < wf_bytes + p_bytes) {
        k_naive<<<dim3(B_SZ), dim3(256), 0, stream>>>(x, idx, W, bias, out);
        return;
    }
    unsigned short* Wf = (unsigned short*)d_ws;
    float* P = (float*)((char*)d_ws + wf_bytes);

    k_build_wf<<<dim3(2048), dim3(256), 0, stream>>>(W, Wf);
    k_gemm<<<dim3(NZB * 8 * (B_SZ / 128)), dim3(256), 0, stream>>>(Wf, x, idx, P);
    k_reduce<<<dim3(2048), dim3(256), 0, stream>>>(P, bias, out);
}